// Round 16
// baseline (140.842 us; speedup 1.0000x reference)
//
#include <hip/hip_runtime.h>

// StickyRNN: B=2048, T=1024, VOCAB=65, EMBED=6, HIDDEN=7
#define TV 65
#define NB 2048
#define NT 1024

typedef float f32x4 __attribute__((ext_vector_type(4)));

// workspace layout (in floats)
#define OFF_SP 0         // SP[cur*65+prev] = float2(Stc, Src)            (2*4225)
#define OFF_LP 8450      // LP[v*65+u]      = float2(Ltc, Lrc)            (2*4225)
#define OFF_S0 16900     // S0[v] = dot(embed[v], hidden_init[0:6])       (65)
#define OFF_TC 16965     // tc[v][k]                                      (65*6)
#define OFF_RC 17355     // rc[v][k]                                      (65*6)
#define OFF_R  17792     // r[b*T+t] reset gate per step                  (2M), 64B-aligned

__global__ __launch_bounds__(128) void k_build1(
    const float* __restrict__ embed, const float* __restrict__ ct,
    const float* __restrict__ rt, const float* __restrict__ hinit,
    float* __restrict__ ws) {
  int v = threadIdx.x;
  if (v >= TV) return;
  float e[6];
#pragma unroll
  for (int k = 0; k < 6; k++) e[k] = embed[v * 6 + k];
#pragma unroll
  for (int j = 0; j < 6; j++) {
    float stc = 0.f, src = 0.f;
#pragma unroll
    for (int k = 0; k < 6; k++) {
      stc += e[k] * ct[k * 6 + j];
      src += e[k] * rt[k * 6 + j];
    }
    ws[OFF_TC + v * 6 + j] = stc;
    ws[OFF_RC + v * 6 + j] = src;
  }
  float s0 = 0.f;
#pragma unroll
  for (int k = 0; k < 6; k++) s0 += e[k] * hinit[k];
  ws[OFF_S0 + v] = s0;
}

__global__ __launch_bounds__(256) void k_build2(
    const float* __restrict__ embed, const float* __restrict__ outw,
    float* __restrict__ ws) {
  int idx = blockIdx.x * 256 + threadIdx.x;
  if (idx >= 2 * 4225) return;
  int tbl = idx / 4225;
  int e2 = idx - tbl * 4225;
  int a = e2 / 65;
  int b = e2 - a * 65;
  if (tbl == 0) {
    float stc = 0.f, src = 0.f;
#pragma unroll
    for (int k = 0; k < 6; k++) {
      stc += embed[a * 6 + k] * ws[OFF_TC + b * 6 + k];
      src += embed[a * 6 + k] * ws[OFF_RC + b * 6 + k];
    }
    ((float2*)(ws + OFF_SP))[e2] = make_float2(stc, src);
  } else {
    float ltc = 0.f, lrc = 0.f;
#pragma unroll
    for (int k = 0; k < 6; k++) {
      ltc += ws[OFF_TC + a * 6 + k] * outw[k * 65 + b];
      lrc += ws[OFF_RC + a * 6 + k] * outw[k * 65 + b];
    }
    ((float2*)(ws + OFF_LP))[e2] = make_float2(ltc, lrc);
  }
}

// Speculative chunk-parallel recurrence (bitwise-verified R2 vs R3; verbatim R8).
__global__ __launch_bounds__(256) void k_rnn_spec(
    const int* __restrict__ x, float* __restrict__ ws,
    const float* __restrict__ thr, const float* __restrict__ temp,
    const float* __restrict__ hinit) {
  __shared__ float2 sSP[4225];
  const float2* __restrict__ gSP = (const float2*)(ws + OFF_SP);
  for (int i = threadIdx.x; i < 4225; i += 256) sSP[i] = gSP[i];
  __syncthreads();

  const int tid = blockIdx.x * 256 + threadIdx.x;  // 0..65535
  const int c = tid >> 11;                         // chunk 0..31 (block-uniform)
  const int row = tid & 2047;
  const int t0 = c * 32;
  int s0 = t0 - 96;
  if (s0 < 0) s0 = 0;
  const bool exact = (s0 == 0);
  const int NG = (t0 + 32 - s0) >> 2;  // 8/16/24/32 groups of 4 steps

  const float t0v = thr[0];
  const float thr2 = t0v * t0v;
  const float invtemp = 1.0f / temp[0];
  const int* xp = x + row * NT;
  float* rbase = ws + OFF_R + row * NT;

  int4 xa = *(const int4*)(xp + s0);
  int4 xb = *(const int4*)(xp + s0 + 4);
  int4 xc = *(const int4*)(xp + s0 + 8);
  int4 xd = *(const int4*)(xp + s0 + 12);

  float pa, r_prev, omr_prev;
  float2 sp0;
  if (exact) {
    float s0v = ws[OFF_S0 + xa.x];
    sp0 = make_float2(s0v, s0v);  // 0.5*s+0.5*s == s exactly
    pa = hinit[6];
    r_prev = 0.5f;
    omr_prev = 0.5f;
  } else {
    int vm1 = xp[s0 - 1];
    sp0 = sSP[xa.x * 65 + vm1];
    pa = 0.0f;
    r_prev = 1.0f;
    omr_prev = 0.0f;
  }
  float2 sp1 = sSP[xa.y * 65 + xa.x];
  float2 sp2 = sSP[xa.z * 65 + xa.y];
  float2 sp3 = sSP[xa.w * 65 + xa.z];

#define STEP(SP, ROUT)                               \
  {                                                  \
    float sim = r_prev * (SP).y + omr_prev * (SP).x; \
    float prod = (1.0f + pa) * sim;                  \
    float aa = fmaxf(prod, 0.0f);                    \
    float add = aa - pa;                             \
    float na = pa + add;                             \
    float p = __expf((thr2 - na) * invtemp);         \
    float r = __builtin_amdgcn_rcpf(1.0f + p);       \
    float omr = 1.0f - r;                            \
    pa = omr * na;                                   \
    r_prev = r;                                      \
    omr_prev = omr;                                  \
    ROUT = r;                                        \
  }

  for (int g = 0; g < NG; ++g) {
    int offn = s0 + 4 * (g + 4);
    if (offn > NT - 4) offn = s0;
    int4 xe = *(const int4*)(xp + offn);
    float2 n0 = sSP[xb.x * 65 + xa.w];
    float2 n1 = sSP[xb.y * 65 + xb.x];
    float2 n2 = sSP[xb.z * 65 + xb.y];
    float2 n3 = sSP[xb.w * 65 + xb.z];

    float4 rq;
    STEP(sp0, rq.x);
    STEP(sp1, rq.y);
    STEP(sp2, rq.z);
    STEP(sp3, rq.w);
    int st = s0 + 4 * g;
    if (st >= t0) *(float4*)(rbase + st) = rq;  // block-uniform branch

    sp0 = n0; sp1 = n1; sp2 = n2; sp3 = n3;
    xa = xb; xb = xc; xc = xd; xd = xe;
  }
#undef STEP
}

// logits[n*65+v] = r_n * Lrc[x_n][v] + (1-r_n) * Ltc[x_n][v]
// R8 body verbatim; ONE change: 512-thread blocks (grid 1024). Same
// 33.8 KB table -> still 4 blocks/CU resident, but 32 waves/CU instead
// of 16 -> 2x in-flight NT-store bytes per CU (Little's law on the
// write path), and table staging cost per element halves.
#define NF4 34078720u   // 2048*1024*65/4
#define PSTRIDE 524288u // 1024*512
__global__ __launch_bounds__(512) void k_proj(
    const int* __restrict__ x, const float* __restrict__ ws,
    float* __restrict__ out) {
  __shared__ float2 sLP[4225];
  const float2* __restrict__ gLP = (const float2*)(ws + OFF_LP);
  for (int i = threadIdx.x; i < 4225; i += 512) sLP[i] = gLP[i];
  __syncthreads();

  unsigned gid = blockIdx.x * 512u + threadIdx.x;
  for (unsigned i4 = gid; i4 < NF4; i4 += PSTRIDE) {
    unsigned base = i4 * 4u;
    unsigned n = base / 65u;
    unsigned v = base - n * 65u;  // 0..64
    unsigned n1 = n + 1u;
    if (n1 > 2097151u) n1 = 2097151u;  // last float4 has v==61: never wraps
    int xv = x[n];
    int xv2 = x[n1];
    float r = ws[OFF_R + n];
    float r2 = ws[OFF_R + n1];
    float omr = 1.0f - r;
    float omr2 = 1.0f - r2;
    unsigned offA = (unsigned)xv * 65u + v;         // element j (no wrap): offA + j
    unsigned offB = (unsigned)xv2 * 65u + v - 65u;  // element j (wrap):    offB + j
    f32x4 o;
#pragma unroll
    for (int j = 0; j < 4; ++j) {
      bool wrap = (v + (unsigned)j) >= 65u;
      unsigned off = (wrap ? offB : offA) + (unsigned)j;
      float2 p = sLP[off];
      float rr = wrap ? r2 : r;
      float oo = wrap ? omr2 : omr;
      o[j] = rr * p.y + oo * p.x;
    }
    __builtin_nontemporal_store(o, (f32x4*)(out + base));
  }
}

extern "C" void kernel_launch(void* const* d_in, const int* in_sizes, int n_in,
                              void* d_out, int out_size, void* d_ws, size_t ws_size,
                              hipStream_t stream) {
  const int* x = (const int*)d_in[0];
  const float* embed = (const float*)d_in[1];
  const float* hinit = (const float*)d_in[2];
  const float* thr = (const float*)d_in[3];
  const float* temp = (const float*)d_in[4];
  const float* ct = (const float*)d_in[5];
  const float* rt = (const float*)d_in[6];
  const float* outw = (const float*)d_in[7];
  float* ws = (float*)d_ws;
  float* out = (float*)d_out;

  hipLaunchKernelGGL(k_build1, dim3(1), dim3(128), 0, stream, embed, ct, rt, hinit, ws);
  hipLaunchKernelGGL(k_build2, dim3((2 * 4225 + 255) / 256), dim3(256), 0, stream,
                     embed, outw, ws);
  hipLaunchKernelGGL(k_rnn_spec, dim3(256), dim3(256), 0, stream, x, ws, thr, temp, hinit);
  hipLaunchKernelGGL(k_proj, dim3(1024), dim3(512), 0, stream, x, ws, out);
}

// Round 17
// 136.484 us; speedup vs baseline: 1.0319x; 1.0319x over previous
//
#include <hip/hip_runtime.h>

// StickyRNN: B=2048, T=1024, VOCAB=65, EMBED=6, HIDDEN=7
// FINAL (R14 config, best measured 136.1 us):
//   k_build1/k_build2: 65x65 dot-product tables (SP) + logit tables (LP)
//   k_rnn_spec: speculative chunk-parallel recurrence (96-step warmup,
//               bitwise-exact vs sequential; verified R2 vs R3)
//   k_proj: branchless LDS-table projection, NT stores, unroll 8
// Roofline: 545 MB output at ~4.5-4.8 TB/s achievable general-data store
// BW (memset's 6.7 TB/s is a special path; 9 single-variable experiments
// bracket this ceiling) + ~8 us recurrence + ~5 us builds.
#define TV 65
#define NB 2048
#define NT 1024

typedef float f32x4 __attribute__((ext_vector_type(4)));

// workspace layout (in floats)
#define OFF_SP 0         // SP[cur*65+prev] = float2(Stc, Src)            (2*4225)
#define OFF_LP 8450      // LP[v*65+u]      = float2(Ltc, Lrc)            (2*4225)
#define OFF_S0 16900     // S0[v] = dot(embed[v], hidden_init[0:6])       (65)
#define OFF_TC 16965     // tc[v][k]                                      (65*6)
#define OFF_RC 17355     // rc[v][k]                                      (65*6)
#define OFF_R  17792     // r[b*T+t] reset gate per step                  (2M), 64B-aligned

__global__ __launch_bounds__(128) void k_build1(
    const float* __restrict__ embed, const float* __restrict__ ct,
    const float* __restrict__ rt, const float* __restrict__ hinit,
    float* __restrict__ ws) {
  int v = threadIdx.x;
  if (v >= TV) return;
  float e[6];
#pragma unroll
  for (int k = 0; k < 6; k++) e[k] = embed[v * 6 + k];
#pragma unroll
  for (int j = 0; j < 6; j++) {
    float stc = 0.f, src = 0.f;
#pragma unroll
    for (int k = 0; k < 6; k++) {
      stc += e[k] * ct[k * 6 + j];
      src += e[k] * rt[k * 6 + j];
    }
    ws[OFF_TC + v * 6 + j] = stc;
    ws[OFF_RC + v * 6 + j] = src;
  }
  float s0 = 0.f;
#pragma unroll
  for (int k = 0; k < 6; k++) s0 += e[k] * hinit[k];
  ws[OFF_S0 + v] = s0;
}

__global__ __launch_bounds__(256) void k_build2(
    const float* __restrict__ embed, const float* __restrict__ outw,
    float* __restrict__ ws) {
  int idx = blockIdx.x * 256 + threadIdx.x;
  if (idx >= 2 * 4225) return;
  int tbl = idx / 4225;
  int e2 = idx - tbl * 4225;
  int a = e2 / 65;
  int b = e2 - a * 65;
  if (tbl == 0) {
    float stc = 0.f, src = 0.f;
#pragma unroll
    for (int k = 0; k < 6; k++) {
      stc += embed[a * 6 + k] * ws[OFF_TC + b * 6 + k];
      src += embed[a * 6 + k] * ws[OFF_RC + b * 6 + k];
    }
    ((float2*)(ws + OFF_SP))[e2] = make_float2(stc, src);
  } else {
    float ltc = 0.f, lrc = 0.f;
#pragma unroll
    for (int k = 0; k < 6; k++) {
      ltc += ws[OFF_TC + a * 6 + k] * outw[k * 65 + b];
      lrc += ws[OFF_RC + a * 6 + k] * outw[k * 65 + b];
    }
    ((float2*)(ws + OFF_LP))[e2] = make_float2(ltc, lrc);
  }
}

// Speculative chunk-parallel recurrence (bitwise-verified R2 vs R3).
__global__ __launch_bounds__(256) void k_rnn_spec(
    const int* __restrict__ x, float* __restrict__ ws,
    const float* __restrict__ thr, const float* __restrict__ temp,
    const float* __restrict__ hinit) {
  __shared__ float2 sSP[4225];
  const float2* __restrict__ gSP = (const float2*)(ws + OFF_SP);
  for (int i = threadIdx.x; i < 4225; i += 256) sSP[i] = gSP[i];
  __syncthreads();

  const int tid = blockIdx.x * 256 + threadIdx.x;  // 0..65535
  const int c = tid >> 11;                         // chunk 0..31 (block-uniform)
  const int row = tid & 2047;
  const int t0 = c * 32;
  int s0 = t0 - 96;
  if (s0 < 0) s0 = 0;
  const bool exact = (s0 == 0);
  const int NG = (t0 + 32 - s0) >> 2;  // 8/16/24/32 groups of 4 steps

  const float t0v = thr[0];
  const float thr2 = t0v * t0v;
  const float invtemp = 1.0f / temp[0];
  const int* xp = x + row * NT;
  float* rbase = ws + OFF_R + row * NT;

  int4 xa = *(const int4*)(xp + s0);
  int4 xb = *(const int4*)(xp + s0 + 4);
  int4 xc = *(const int4*)(xp + s0 + 8);
  int4 xd = *(const int4*)(xp + s0 + 12);

  float pa, r_prev, omr_prev;
  float2 sp0;
  if (exact) {
    float s0v = ws[OFF_S0 + xa.x];
    sp0 = make_float2(s0v, s0v);  // 0.5*s+0.5*s == s exactly
    pa = hinit[6];
    r_prev = 0.5f;
    omr_prev = 0.5f;
  } else {
    int vm1 = xp[s0 - 1];
    sp0 = sSP[xa.x * 65 + vm1];
    pa = 0.0f;
    r_prev = 1.0f;
    omr_prev = 0.0f;
  }
  float2 sp1 = sSP[xa.y * 65 + xa.x];
  float2 sp2 = sSP[xa.z * 65 + xa.y];
  float2 sp3 = sSP[xa.w * 65 + xa.z];

#define STEP(SP, ROUT)                               \
  {                                                  \
    float sim = r_prev * (SP).y + omr_prev * (SP).x; \
    float prod = (1.0f + pa) * sim;                  \
    float aa = fmaxf(prod, 0.0f);                    \
    float add = aa - pa;                             \
    float na = pa + add;                             \
    float p = __expf((thr2 - na) * invtemp);         \
    float r = __builtin_amdgcn_rcpf(1.0f + p);       \
    float omr = 1.0f - r;                            \
    pa = omr * na;                                   \
    r_prev = r;                                      \
    omr_prev = omr;                                  \
    ROUT = r;                                        \
  }

  for (int g = 0; g < NG; ++g) {
    int offn = s0 + 4 * (g + 4);
    if (offn > NT - 4) offn = s0;
    int4 xe = *(const int4*)(xp + offn);
    float2 n0 = sSP[xb.x * 65 + xa.w];
    float2 n1 = sSP[xb.y * 65 + xb.x];
    float2 n2 = sSP[xb.z * 65 + xb.y];
    float2 n3 = sSP[xb.w * 65 + xb.z];

    float4 rq;
    STEP(sp0, rq.x);
    STEP(sp1, rq.y);
    STEP(sp2, rq.z);
    STEP(sp3, rq.w);
    int st = s0 + 4 * g;
    if (st >= t0) *(float4*)(rbase + st) = rq;  // block-uniform branch

    sp0 = n0; sp1 = n1; sp2 = n2; sp3 = n3;
    xa = xb; xb = xc; xc = xd; xd = xe;
  }
#undef STEP
}

// logits[n*65+v] = r_n * Lrc[x_n][v] + (1-r_n) * Ltc[x_n][v]
// R14 best: 2048 blocks x 256, branchless, LDS-LP, NT store, unroll 8.
#define NF4 34078720u   // 2048*1024*65/4
#define PSTRIDE 524288u // 2048*256
__global__ __launch_bounds__(256) void k_proj(
    const int* __restrict__ x, const float* __restrict__ ws,
    float* __restrict__ out) {
  __shared__ float2 sLP[4225];
  const float2* __restrict__ gLP = (const float2*)(ws + OFF_LP);
  for (int i = threadIdx.x; i < 4225; i += 256) sLP[i] = gLP[i];
  __syncthreads();

  unsigned gid = blockIdx.x * 256u + threadIdx.x;
#pragma unroll 8
  for (unsigned i4 = gid; i4 < NF4; i4 += PSTRIDE) {
    unsigned base = i4 * 4u;
    unsigned n = base / 65u;
    unsigned v = base - n * 65u;  // 0..64
    unsigned n1 = n + 1u;
    if (n1 > 2097151u) n1 = 2097151u;  // last float4 has v==61: never wraps
    int xv = x[n];
    int xv2 = x[n1];
    float r = ws[OFF_R + n];
    float r2 = ws[OFF_R + n1];
    float omr = 1.0f - r;
    float omr2 = 1.0f - r2;
    unsigned offA = (unsigned)xv * 65u + v;         // element j (no wrap): offA + j
    unsigned offB = (unsigned)xv2 * 65u + v - 65u;  // element j (wrap):    offB + j
    f32x4 o;
#pragma unroll
    for (int j = 0; j < 4; ++j) {
      bool wrap = (v + (unsigned)j) >= 65u;
      unsigned off = (wrap ? offB : offA) + (unsigned)j;
      float2 p = sLP[off];
      float rr = wrap ? r2 : r;
      float oo = wrap ? omr2 : omr;
      o[j] = rr * p.y + oo * p.x;
    }
    __builtin_nontemporal_store(o, (f32x4*)(out + base));
  }
}

extern "C" void kernel_launch(void* const* d_in, const int* in_sizes, int n_in,
                              void* d_out, int out_size, void* d_ws, size_t ws_size,
                              hipStream_t stream) {
  const int* x = (const int*)d_in[0];
  const float* embed = (const float*)d_in[1];
  const float* hinit = (const float*)d_in[2];
  const float* thr = (const float*)d_in[3];
  const float* temp = (const float*)d_in[4];
  const float* ct = (const float*)d_in[5];
  const float* rt = (const float*)d_in[6];
  const float* outw = (const float*)d_in[7];
  float* ws = (float*)d_ws;
  float* out = (float*)d_out;

  hipLaunchKernelGGL(k_build1, dim3(1), dim3(128), 0, stream, embed, ct, rt, hinit, ws);
  hipLaunchKernelGGL(k_build2, dim3((2 * 4225 + 255) / 256), dim3(256), 0, stream,
                     embed, outw, ws);
  hipLaunchKernelGGL(k_rnn_spec, dim3(256), dim3(256), 0, stream, x, ws, thr, temp, hinit);
  hipLaunchKernelGGL(k_proj, dim3(2048), dim3(256), 0, stream, x, ws, out);
}